// Round 1
// baseline (232.283 us; speedup 1.0000x reference)
//
#include <hip/hip_runtime.h>

typedef __attribute__((ext_vector_type(8))) short short8;
typedef __attribute__((ext_vector_type(4))) float f32x4;
typedef unsigned short u16;

#define SCALE 0.125f

#define BB 16
#define LL 1024
#define CC 512
#define HH 8
#define DD 64
#define MROWS (BB*LL)      /* 16384 */
#define KPROJ 1024
#define NPROJ 1536

#define BM 128
#define BN 128
#define BK 32

// workspace offsets (bytes)
#define WS_XCAT   0ull
#define WS_WCAT   (WS_XCAT + (size_t)MROWS*KPROJ*2)   /* 33,554,432 */
#define WS_WO     (WS_WCAT + (size_t)NPROJ*KPROJ*2)
#define WS_BIAS   (WS_WO   + (size_t)CC*CC*2)
#define WS_QH     (WS_BIAS + 8192)
#define WS_KH     (WS_QH + (size_t)MROWS*CC*2)
#define WS_VH     (WS_KH + (size_t)MROWS*CC*2)
#define WS_OH     (WS_VH + (size_t)MROWS*CC*2)
#define WS_END    (WS_OH + (size_t)MROWS*CC*2)

__device__ inline short f2bf(float f) {
  unsigned u = __builtin_bit_cast(unsigned, f);
  u = (u + 0x7FFFu + ((u >> 16) & 1u)) >> 16;
  return (short)u;
}

__device__ inline short8 pack8(const float* src) {
  float4 a = ((const float4*)src)[0];
  float4 b = ((const float4*)src)[1];
  short8 v;
  v[0]=f2bf(a.x); v[1]=f2bf(a.y); v[2]=f2bf(a.z); v[3]=f2bf(a.w);
  v[4]=f2bf(b.x); v[5]=f2bf(b.y); v[6]=f2bf(b.z); v[7]=f2bf(b.w);
  return v;
}

__device__ inline void gload_lds16(const u16* g, char* lds_byte) {
  __builtin_amdgcn_global_load_lds(
      (const __attribute__((address_space(1))) unsigned int*)g,
      (__attribute__((address_space(3))) unsigned int*)lds_byte,
      16, 0, 0);
}

// ---------------- pack kernels ----------------

__global__ __launch_bounds__(256) void pack_x_kernel(
    const float* __restrict__ q, const float* __restrict__ qp, u16* __restrict__ xcat) {
  int o = blockIdx.x * 256 + threadIdx.x;     // octet id over 16384*128
  int row = o >> 7;
  int kk  = (o & 127) << 3;
  const float* src = (kk < 512) ? (q + (size_t)row * 512 + kk)
                                : (qp + (size_t)row * 512 + (kk - 512));
  short8 v = pack8(src);
  *(short8*)(xcat + (size_t)row * KPROJ + kk) = v;
}

__global__ __launch_bounds__(256) void pack_w_kernel(
    const float* __restrict__ Wqc, const float* __restrict__ Wqp,
    const float* __restrict__ Wkc, const float* __restrict__ Wkp,
    const float* __restrict__ Wv,  const float* __restrict__ Wo,
    const float* __restrict__ bqc, const float* __restrict__ bqp,
    const float* __restrict__ bkc, const float* __restrict__ bkp,
    const float* __restrict__ bv,
    u16* __restrict__ wcat, u16* __restrict__ wo_bf, float* __restrict__ bias_cat) {
  int o = blockIdx.x * 256 + threadIdx.x;
  if (o < 196608) {  // Wcat: 1536 rows x 128 octets
    int j = o >> 7;
    int kk = (o & 127) << 3;
    const float* src = nullptr;
    if (j < 512)        src = (kk < 512) ? Wqc + (size_t)j * 512 + kk : Wqp + (size_t)j * 512 + (kk - 512);
    else if (j < 1024) { int jj = j - 512;  src = (kk < 512) ? Wkc + (size_t)jj * 512 + kk : Wkp + (size_t)jj * 512 + (kk - 512); }
    else               { int jj = j - 1024; src = (kk < 512) ? Wv  + (size_t)jj * 512 + kk : nullptr; }
    short8 v = {0,0,0,0,0,0,0,0};
    if (src) v = pack8(src);
    *(short8*)(wcat + (size_t)j * KPROJ + kk) = v;
  } else if (o < 229376) {  // Wo: 512 rows x 64 octets
    int o2 = o - 196608;
    int j = o2 >> 6;
    int kk = (o2 & 63) << 3;
    short8 v = pack8(Wo + (size_t)j * 512 + kk);
    *(short8*)(wo_bf + (size_t)j * 512 + kk) = v;
  }
  if (o < 1536) {
    float v;
    if (o < 512)       v = bqc[o] + bqp[o];
    else if (o < 1024) v = bkc[o - 512] + bkp[o - 512];
    else               v = bv[o - 1024];
    bias_cat[o] = v;
  }
}

// ---------------- GEMM core ----------------
// C[m0..+128, n0..+128] += A[m,k] * B[n,k]  (both K-major, bf16), acc fp32.
template <int KDIM>
__device__ inline void gemm_mainloop(const u16* __restrict__ A, const u16* __restrict__ Bw,
                                     int m0, int n0,
                                     u16* Alds, u16* Blds,   // each 2*BM*BK elems
                                     f32x4 (&acc)[4][4]) {
  const int tid = threadIdx.x;
  const int lane = tid & 63, wave = tid >> 6;
  const int wr = wave >> 1, wc = wave & 1;
  const int lr = lane & 15, lg = lane >> 4;

  auto stage = [&](int buf, int t) {
    int k0 = t * BK;
    #pragma unroll
    for (int i = 0; i < 2; ++i) {
      int c = (i * 4 + wave) * 64 + lane;       // chunk id 0..511
      int row = c >> 2, koct = c & 3;
      char* ldsbaseA = (char*)Alds + (size_t)buf * (BM * BK * 2) + (size_t)(i * 4 + wave) * 1024;
      char* ldsbaseB = (char*)Blds + (size_t)buf * (BN * BK * 2) + (size_t)(i * 4 + wave) * 1024;
      gload_lds16(A  + (size_t)(m0 + row) * KDIM + k0 + koct * 8, ldsbaseA);
      gload_lds16(Bw + (size_t)(n0 + row) * KDIM + k0 + koct * 8, ldsbaseB);
    }
  };

  stage(0, 0);
  constexpr int NT = KDIM / BK;
  int cur = 0;
  for (int t = 0; t < NT; ++t) {
    __syncthreads();
    if (t + 1 < NT) stage(cur ^ 1, t + 1);
    const u16* Ab = Alds + (size_t)cur * (BM * BK);
    const u16* Bb = Blds + (size_t)cur * (BN * BK);
    short8 af[4], bfr[4];
    #pragma unroll
    for (int m = 0; m < 4; ++m)
      af[m] = *(const short8*)(Ab + (size_t)(wr * 64 + m * 16 + lr) * BK + lg * 8);
    #pragma unroll
    for (int n = 0; n < 4; ++n)
      bfr[n] = *(const short8*)(Bb + (size_t)(wc * 64 + n * 16 + lr) * BK + lg * 8);
    #pragma unroll
    for (int m = 0; m < 4; ++m)
      #pragma unroll
      for (int n = 0; n < 4; ++n)
        acc[m][n] = __builtin_amdgcn_mfma_f32_16x16x32_bf16(af[m], bfr[n], acc[m][n], 0, 0, 0);
    cur ^= 1;
  }
}

// ---------------- projection GEMM ----------------
__global__ __launch_bounds__(256) void proj_gemm_kernel(
    const u16* __restrict__ Xcat, const u16* __restrict__ Wcat,
    const float* __restrict__ bias_cat,
    u16* __restrict__ Qh, u16* __restrict__ Kh, u16* __restrict__ Vh) {
  __shared__ __align__(16) u16 Alds[2 * BM * BK];
  __shared__ __align__(16) u16 Blds[2 * BN * BK];
  int m0 = blockIdx.x * BM, n0 = blockIdx.y * BN;
  f32x4 acc[4][4];
  f32x4 z4 = {0.f, 0.f, 0.f, 0.f};
  #pragma unroll
  for (int m = 0; m < 4; ++m)
    #pragma unroll
    for (int n = 0; n < 4; ++n) acc[m][n] = z4;

  gemm_mainloop<KPROJ>(Xcat, Wcat, m0, n0, Alds, Blds, acc);

  const int lane = threadIdx.x & 63, wave = threadIdx.x >> 6;
  const int wr = wave >> 1, wc = wave & 1;
  const int lr = lane & 15, lg = lane >> 4;
  #pragma unroll
  for (int m = 0; m < 4; ++m) {
    int rowb = m0 + wr * 64 + m * 16 + lg * 4;
    #pragma unroll
    for (int n = 0; n < 4; ++n) {
      int col = n0 + wc * 64 + n * 16 + lr;
      float bias = bias_cat[col];
      int sec = col >> 9;
      int cj = col & 511;
      int h = cj >> 6, d = cj & 63;
      u16* dstbuf = (sec == 0) ? Qh : (sec == 1) ? Kh : Vh;
      float scl = (sec == 0) ? SCALE : 1.0f;
      #pragma unroll
      for (int r = 0; r < 4; ++r) {
        int rw = rowb + r;
        int b = rw >> 10, l = rw & 1023;
        float v = (acc[m][n][r] + bias) * scl;
        dstbuf[((size_t)(b * HH + h) * LL + l) * DD + d] = (u16)f2bf(v);
      }
    }
  }
}

// ---------------- flash attention ----------------
// grid: (L/64, B*H). 4 waves, each owns 16 q rows. KV tiles of 64.
__global__ __launch_bounds__(256) void attn_kernel(
    const u16* __restrict__ Qh, const u16* __restrict__ Kh,
    const u16* __restrict__ Vh, u16* __restrict__ Oh) {
  __shared__ __align__(16) u16 Klds[64 * 64];      // swizzled chunks
  __shared__ __align__(16) u16 Vt[64 * 64];        // V^T, swizzled chunks
  __shared__ __align__(16) u16 Plds[4][16 * 72];   // per-wave P tile

  const int tid = threadIdx.x;
  const int lane = tid & 63, wave = tid >> 6;
  const int lr = lane & 15, lg = lane >> 4;
  const int q0 = blockIdx.x * 64;
  const int bh = blockIdx.y;

  const u16* Qb = Qh + (size_t)bh * LL * DD;
  const u16* Kb = Kh + (size_t)bh * LL * DD;
  const u16* Vb = Vh + (size_t)bh * LL * DD;

  // Q fragments (A-operand): row = q0 + wave*16 + lr, k = s*32 + lg*8 ..+8
  short8 aq[2];
  #pragma unroll
  for (int s = 0; s < 2; ++s)
    aq[s] = *(const short8*)(Qb + (size_t)(q0 + wave * 16 + lr) * DD + s * 32 + lg * 8);

  f32x4 z4 = {0.f, 0.f, 0.f, 0.f};
  f32x4 oacc[4];
  #pragma unroll
  for (int n = 0; n < 4; ++n) oacc[n] = z4;
  float mrow[4], lsum[4];
  #pragma unroll
  for (int r = 0; r < 4; ++r) { mrow[r] = -1e30f; lsum[r] = 0.f; }

  for (int kt = 0; kt < 16; ++kt) {
    int kk0 = kt * 64;
    __syncthreads();  // previous tile's reads done before overwrite

    // stage K tile via global_load_lds with source-side XOR swizzle
    #pragma unroll
    for (int i = 0; i < 2; ++i) {
      int c = (i * 4 + wave) * 64 + lane;   // 0..511
      int row = c >> 3, koct = c & 7;
      int ks = koct ^ (row & 7);
      gload_lds16(Kb + (size_t)(kk0 + row) * DD + ks * 8,
                  (char*)Klds + (size_t)(i * 4 + wave) * 1024);
    }
    // stage V^T: coalesced 2B loads, swizzled b128 LDS writes
    {
      int d = tid & 63;
      #pragma unroll
      for (int i = 0; i < 2; ++i) {
        int kg = (tid >> 6) + i * 4;   // key-octet 0..7
        short8 vv;
        #pragma unroll
        for (int j = 0; j < 8; ++j)
          vv[j] = (short)Vb[(size_t)(kk0 + kg * 8 + j) * DD + d];
        *(short8*)((char*)Vt + (size_t)d * 128 + ((kg ^ (d & 7)) << 4)) = vv;
      }
    }
    __syncthreads();

    // S = Q @ K^T  (16 q-rows x 64 keys per wave)
    f32x4 sacc[4];
    #pragma unroll
    for (int nb = 0; nb < 4; ++nb) sacc[nb] = z4;
    #pragma unroll
    for (int s = 0; s < 2; ++s) {
      #pragma unroll
      for (int nb = 0; nb < 4; ++nb) {
        int key = nb * 16 + lr;
        int dct = s * 4 + lg;
        short8 bk = *(const short8*)((const char*)Klds + (size_t)key * 128 + ((dct ^ (key & 7)) << 4));
        sacc[nb] = __builtin_amdgcn_mfma_f32_16x16x32_bf16(aq[s], bk, sacc[nb], 0, 0, 0);
      }
    }

    // online softmax (rows owned: lg*4 + r; reduce across lanes lr 0..15)
    float rmax[4];
    #pragma unroll
    for (int r = 0; r < 4; ++r) {
      float v = sacc[0][r];
      #pragma unroll
      for (int nb = 1; nb < 4; ++nb) v = fmaxf(v, sacc[nb][r]);
      v = fmaxf(v, __shfl_xor(v, 1));
      v = fmaxf(v, __shfl_xor(v, 2));
      v = fmaxf(v, __shfl_xor(v, 4));
      v = fmaxf(v, __shfl_xor(v, 8));
      rmax[r] = v;
    }
    float alpha[4];
    #pragma unroll
    for (int r = 0; r < 4; ++r) {
      float mn = fmaxf(mrow[r], rmax[r]);
      alpha[r] = __expf(mrow[r] - mn);
      mrow[r] = mn;
    }
    float rsum[4] = {0.f, 0.f, 0.f, 0.f};
    #pragma unroll
    for (int nb = 0; nb < 4; ++nb)
      #pragma unroll
      for (int r = 0; r < 4; ++r) {
        float p = __expf(sacc[nb][r] - mrow[r]);
        sacc[nb][r] = p;
        rsum[r] += p;
      }
    // write P (bf16) to per-wave LDS
    #pragma unroll
    for (int nb = 0; nb < 4; ++nb)
      #pragma unroll
      for (int r = 0; r < 4; ++r)
        Plds[wave][(size_t)(lg * 4 + r) * 72 + nb * 16 + lr] = (u16)f2bf(sacc[nb][r]);
    #pragma unroll
    for (int r = 0; r < 4; ++r) {
      float v = rsum[r];
      v += __shfl_xor(v, 1);
      v += __shfl_xor(v, 2);
      v += __shfl_xor(v, 4);
      v += __shfl_xor(v, 8);
      lsum[r] = lsum[r] * alpha[r] + v;
      #pragma unroll
      for (int nb = 0; nb < 4; ++nb) oacc[nb][r] *= alpha[r];
    }

    // O += P @ V
    #pragma unroll
    for (int s = 0; s < 2; ++s) {
      short8 ap = *(const short8*)(&Plds[wave][(size_t)lr * 72 + s * 32 + lg * 8]);
      #pragma unroll
      for (int nb = 0; nb < 4; ++nb) {
        int dd = nb * 16 + lr;
        int kc = s * 4 + lg;
        short8 bv = *(const short8*)((const char*)Vt + (size_t)dd * 128 + ((kc ^ (dd & 7)) << 4));
        oacc[nb] = __builtin_amdgcn_mfma_f32_16x16x32_bf16(ap, bv, oacc[nb], 0, 0, 0);
      }
    }
  }

  // epilogue: O /= lsum, write [B,L,C] bf16
  int b = bh >> 3, h = bh & 7;
  float inv[4];
  #pragma unroll
  for (int r = 0; r < 4; ++r) inv[r] = 1.0f / lsum[r];
  #pragma unroll
  for (int nb = 0; nb < 4; ++nb)
    #pragma unroll
    for (int r = 0; r < 4; ++r) {
      int q = q0 + wave * 16 + lg * 4 + r;
      int col = h * 64 + nb * 16 + lr;
      float v = oacc[nb][r] * inv[r];
      Oh[(size_t)(b * LL + q) * CC + col] = (u16)f2bf(v);
    }
}

// ---------------- output projection + residual ----------------
__global__ __launch_bounds__(256) void out_gemm_kernel(
    const u16* __restrict__ Oh, const u16* __restrict__ Wo_bf,
    const float* __restrict__ bo, const float* __restrict__ query,
    float* __restrict__ out) {
  __shared__ __align__(16) u16 Alds[2 * BM * BK];
  __shared__ __align__(16) u16 Blds[2 * BN * BK];
  int m0 = blockIdx.x * BM, n0 = blockIdx.y * BN;
  f32x4 acc[4][4];
  f32x4 z4 = {0.f, 0.f, 0.f, 0.f};
  #pragma unroll
  for (int m = 0; m < 4; ++m)
    #pragma unroll
    for (int n = 0; n < 4; ++n) acc[m][n] = z4;

  gemm_mainloop<CC>(Oh, Wo_bf, m0, n0, Alds, Blds, acc);

  const int lane = threadIdx.x & 63, wave = threadIdx.x >> 6;
  const int wr = wave >> 1, wc = wave & 1;
  const int lr = lane & 15, lg = lane >> 4;
  #pragma unroll
  for (int m = 0; m < 4; ++m) {
    int rowb = m0 + wr * 64 + m * 16 + lg * 4;
    #pragma unroll
    for (int n = 0; n < 4; ++n) {
      int col = n0 + wc * 64 + n * 16 + lr;
      float bias = bo[col];
      #pragma unroll
      for (int r = 0; r < 4; ++r) {
        int rw = rowb + r;
        size_t idx = (size_t)rw * CC + col;
        out[idx] = acc[m][n][r] + bias + query[idx];
      }
    }
  }
}

// ---------------- launcher ----------------
extern "C" void kernel_launch(void* const* d_in, const int* in_sizes, int n_in,
                              void* d_out, int out_size, void* d_ws, size_t ws_size,
                              hipStream_t stream) {
  (void)in_sizes; (void)n_in; (void)out_size;
  const float* query = (const float*)d_in[0];
  const float* qpos  = (const float*)d_in[1];
  const float* Wqc = (const float*)d_in[2];
  const float* bqc = (const float*)d_in[3];
  const float* Wqp = (const float*)d_in[4];
  const float* bqp = (const float*)d_in[5];
  const float* Wkc = (const float*)d_in[6];
  const float* bkc = (const float*)d_in[7];
  const float* Wkp = (const float*)d_in[8];
  const float* bkp = (const float*)d_in[9];
  const float* Wv  = (const float*)d_in[10];
  const float* bv  = (const float*)d_in[11];
  const float* Wo  = (const float*)d_in[12];
  const float* bo  = (const float*)d_in[13];

  char* ws = (char*)d_ws;
  if (ws_size < WS_END) return;  // insufficient scratch -> fail loudly via mismatch

  u16*   Xcat     = (u16*)(ws + WS_XCAT);
  u16*   Wcat     = (u16*)(ws + WS_WCAT);
  u16*   Wo_bf    = (u16*)(ws + WS_WO);
  float* bias_cat = (float*)(ws + WS_BIAS);
  u16*   Qh       = (u16*)(ws + WS_QH);
  u16*   Kh       = (u16*)(ws + WS_KH);
  u16*   Vh       = (u16*)(ws + WS_VH);
  u16*   Oh       = (u16*)(ws + WS_OH);
  float* out      = (float*)d_out;

  pack_x_kernel<<<dim3(8192), dim3(256), 0, stream>>>(query, qpos, Xcat);
  pack_w_kernel<<<dim3(896), dim3(256), 0, stream>>>(Wqc, Wqp, Wkc, Wkp, Wv, Wo,
                                                     bqc, bqp, bkc, bkp, bv,
                                                     Wcat, Wo_bf, bias_cat);
  proj_gemm_kernel<<<dim3(MROWS / BM, NPROJ / BN), dim3(256), 0, stream>>>(
      Xcat, Wcat, bias_cat, Qh, Kh, Vh);
  attn_kernel<<<dim3(LL / 64, BB * HH), dim3(256), 0, stream>>>(Qh, Kh, Vh, Oh);
  out_gemm_kernel<<<dim3(MROWS / BM, CC / BN), dim3(256), 0, stream>>>(
      Oh, Wo_bf, bo, query, out);
}